// Round 2
// baseline (84.260 us; speedup 1.0000x reference)
//
#include <hip/hip_runtime.h>
#include <hip/hip_bf16.h>

// Chamfer loss, N=8, V=4096, C=3, fp32.
// loss = (sum over all 2*N*V points of sqrt(min squared dist to other set)) / (N*V)

#define N_BATCH 8
#define V 4096
#define TPB 256
#define PX 4                 // A-points per thread
#define VBLK (TPB * PX)      // 1024 A-points per block
#define NVB (V / VBLK)       // 4
#define NYC 8                // B-axis chunks
#define YC (V / NYC)         // 512 B-points per chunk
#define NPTS (N_BATCH * V)   // 32768 per direction

__global__ __launch_bounds__(256) void chamfer_init(unsigned int* __restrict__ wmin,
                                                    float* __restrict__ out) {
    int i = blockIdx.x * 256 + threadIdx.x;
    if (i < 2 * NPTS) wmin[i] = 0x7F800000u;  // +inf
    if (i == 0) out[0] = 0.0f;
}

__global__ __launch_bounds__(TPB) void chamfer_main(const float* __restrict__ x,
                                                    const float* __restrict__ y,
                                                    unsigned int* __restrict__ wmin) {
    __shared__ float4 sb[YC];

    int bid = blockIdx.x;
    int yc  = bid % NYC;      bid /= NYC;
    int vb  = bid % NVB;      bid /= NVB;
    int n   = bid % N_BATCH;  bid /= N_BATCH;
    int dir = bid;            // 0: A=x,B=y ; 1: A=y,B=x

    const float* A = dir ? y : x;
    const float* B = dir ? x : y;
    const float* Abase = A + (size_t)n * V * 3;
    const float* Bbase = B + (size_t)n * V * 3 + (size_t)yc * YC * 3;

    // Stage B-chunk into LDS as (bx, by, bz, ||b||^2)
    for (int i = threadIdx.x; i < YC; i += TPB) {
        float b0 = Bbase[3 * i + 0];
        float b1 = Bbase[3 * i + 1];
        float b2 = Bbase[3 * i + 2];
        sb[i] = make_float4(b0, b1, b2, b0 * b0 + b1 * b1 + b2 * b2);
    }
    __syncthreads();

    // Per-thread A-points: pre-scale by -2, precompute norms
    float nx0[PX], nx1[PX], nx2[PX], pxs[PX], m[PX];
    const int pbase = vb * VBLK + threadIdx.x;
#pragma unroll
    for (int p = 0; p < PX; ++p) {
        const float* ap = Abase + 3 * (pbase + p * TPB);
        float a0 = ap[0], a1 = ap[1], a2 = ap[2];
        nx0[p] = -2.0f * a0;
        nx1[p] = -2.0f * a1;
        nx2[p] = -2.0f * a2;
        pxs[p] = a0 * a0 + a1 * a1 + a2 * a2;
        m[p] = 1e30f;
    }

    // 5 VALU ops per pair: add, 3x fma, min. One ds_read_b128 per 20 VALU.
#pragma unroll 4
    for (int j = 0; j < YC; ++j) {
        float4 bv = sb[j];
#pragma unroll
        for (int p = 0; p < PX; ++p) {
            float t = pxs[p] + bv.w;
            t = fmaf(nx0[p], bv.x, t);
            t = fmaf(nx1[p], bv.y, t);
            t = fmaf(nx2[p], bv.z, t);
            m[p] = fminf(m[p], t);
        }
    }

    unsigned int* wout = wmin + dir * NPTS + n * V;
#pragma unroll
    for (int p = 0; p < PX; ++p) {
        float v = fmaxf(m[p], 0.0f);  // clamp: nonneg floats are bit-monotone
        atomicMin(&wout[pbase + p * TPB], __float_as_uint(v));
    }
}

#define RBLOCKS 32
__global__ __launch_bounds__(256) void chamfer_reduce(const unsigned int* __restrict__ wmin,
                                                      float* __restrict__ out) {
    __shared__ float ssum[4];
    const int T = RBLOCKS * 256;
    int tid = blockIdx.x * 256 + threadIdx.x;
    float s = 0.0f;
    for (int t = tid; t < 2 * NPTS; t += T) {
        s += sqrtf(__uint_as_float(wmin[t]));
    }
    // wave reduce (64 lanes)
    for (int off = 32; off > 0; off >>= 1) s += __shfl_down(s, off);
    int lane = threadIdx.x & 63, wid = threadIdx.x >> 6;
    if (lane == 0) ssum[wid] = s;
    __syncthreads();
    if (threadIdx.x == 0) {
        float tot = ssum[0] + ssum[1] + ssum[2] + ssum[3];
        atomicAdd(out, tot * (1.0f / (float)NPTS));
    }
}

extern "C" void kernel_launch(void* const* d_in, const int* in_sizes, int n_in,
                              void* d_out, int out_size, void* d_ws, size_t ws_size,
                              hipStream_t stream) {
    const float* x = (const float*)d_in[0];
    const float* y = (const float*)d_in[1];
    float* out = (float*)d_out;
    unsigned int* wmin = (unsigned int*)d_ws;  // 2*NPTS*4 = 256 KB

    // 1) init mins to +inf, zero the output scalar
    chamfer_init<<<(2 * NPTS + 255) / 256, 256, 0, stream>>>(wmin, out);

    // 2) both directions: 2 * 8 * 4 * 8 = 512 blocks
    int nblocks = 2 * N_BATCH * NVB * NYC;
    chamfer_main<<<nblocks, TPB, 0, stream>>>(x, y, wmin);

    // 3) sqrt + mean reduce into d_out
    chamfer_reduce<<<RBLOCKS, 256, 0, stream>>>(wmin, out);
}